// Round 9
// baseline (118.068 us; speedup 1.0000x reference)
//
#include <hip/hip_runtime.h>

// Relation Graph Attention (RGAT), MI355X. v9 (= v8 with bits_lds stride fix).
// R=3, B=2, N=2048, CIN=256, NH=4, D=64.
//  K0 : W -> Wt bf16 [r][o][k]; Wout -> WoT bf16 [o][k]
//  K1 : per (r,b,itile64,head): hs-tile = xs @ W[r][:,head] (MFMA);
//       epilogue: eip/ein f32 + ej2 = packed {bf16 exp2(sj), bf16 exp2(.1 sj)};
//       V frag-tiled store; (r0,h0) blocks also compute xo = xs @ W_out.
//  K2 : per (r,b,itile16): 8 waves = 4 heads x 2 j-halves.
//       PROLOGUE: ballot-pack adj rows -> bitmask in LDS (64 u32/row + pad).
//       J-LOOP: barrier-free; per lane 8 mask bits/sub; P = bit ? max(eip*ejp,
//       ein*ejn) : 0; P@V MFMA + den ones-MFMA. Cross-q merge, num[r] store.
//  K3 : out = xo_broadcast + sum_r num[r]

constexpr int R_ = 3, B_ = 2, N_ = 2048, CIN_ = 256, NH_ = 4, D_ = 64, NHD_ = 256;
constexpr int IT2_ = 16;               // i rows per K2 block
constexpr int BROW_ = 65;              // u32 per bitmask row (64 data + 1 pad)
constexpr float LEAKY = 0.1f;
constexpr float LOG2E = 1.4426950408889634f;

typedef float f32x4 __attribute__((ext_vector_type(4)));
typedef __bf16 bf16x8 __attribute__((ext_vector_type(8)));

// workspace layout (bytes)
constexpr size_t OFF_WT  = 0;                                      // ushort [R][NHD][CIN]
constexpr size_t SZ_WT   = (size_t)R_ * NHD_ * CIN_ * 2;           // 393216
constexpr size_t OFF_WOT = OFF_WT + SZ_WT;                         // ushort [D][CIN]
constexpr size_t SZ_WOT  = (size_t)D_ * CIN_ * 2;                  // 32768
constexpr size_t OFF_VT  = OFF_WOT + SZ_WOT;                       // ushort, frag-tiled
constexpr size_t SZ_VT   = (size_t)R_ * B_ * NH_ * D_ * N_ * 2;
constexpr size_t SZ_E    = (size_t)R_ * B_ * NH_ * N_ * 4;         // [R][B][NH][N]
constexpr size_t OFF_EIP = OFF_VT + SZ_VT;
constexpr size_t OFF_EIN = OFF_EIP + SZ_E;
constexpr size_t OFF_EJ2 = OFF_EIN + SZ_E;                         // u32 packed bf16 pair
constexpr size_t OFF_XO  = OFF_EJ2 + SZ_E;                         // float [B][N][D]
constexpr size_t SZ_XO   = (size_t)B_ * N_ * D_ * 4;
constexpr size_t OFF_NUM = OFF_XO + SZ_XO;                         // float [R][B][N][NHD]

__device__ __forceinline__ unsigned short f2bf_bits(float f) {
    __bf16 b = (__bf16)f;
    return __builtin_bit_cast(unsigned short, b);
}

// ---------------- K0: transpose+cast W and Wout ----------------
__global__ void k0_wt(const float* __restrict__ W, const float* __restrict__ Wout,
                      unsigned short* __restrict__ Wt, unsigned short* __restrict__ WoT) {
    int of = blockIdx.x * 256 + threadIdx.x;       // 0..212991
    if (of < 196608) {
        int r = of >> 16;
        int rem = of & 65535;
        int o = rem >> 8;
        int k = rem & 255;
        Wt[of] = f2bf_bits(W[((size_t)(r * CIN_ + k)) * NHD_ + o]);
    } else {
        int idx = of - 196608;                     // 0..16383
        int o = idx >> 8, k = idx & 255;
        WoT[idx] = f2bf_bits(Wout[k * D_ + o]);
    }
}

// ---------------- K1: per-head hs GEMM + factored-exp epilogue + frag-tiled V ----------------
// grid: R*B*32*4 = 768 blocks, 256 threads (4 waves x 16 rows); head = blockIdx&3
__global__ __launch_bounds__(256) void k1_hs(const float* __restrict__ xs,
                                             const unsigned short* __restrict__ Wt,
                                             const unsigned short* __restrict__ WoT,
                                             const float* __restrict__ al,
                                             const float* __restrict__ ar,
                                             unsigned short* __restrict__ Vt,
                                             float* __restrict__ eip,
                                             float* __restrict__ ein,
                                             unsigned int* __restrict__ ej2,
                                             float* __restrict__ xo) {
    __shared__ unsigned short lds2[64][72];

    int x = blockIdx.x;
    int ct = x & 3;                        // head
    int itile = (x >> 2) & 31;
    int b = (x >> 7) & 1;
    int r = x >> 8;
    int tid = threadIdx.x;
    int l = tid & 63;
    int w = tid >> 6;
    int l15 = l & 15;
    int lg = l >> 4;
    int n0 = itile * 64;
    bool do_xo = (r == 0) && (ct == 0);

    const float* xrow = xs + ((size_t)(b * N_ + n0 + w * 16 + l15)) * CIN_;
    const unsigned short* wt_base = Wt + ((size_t)r * NHD_ + ct * 64) * CIN_;

    f32x4 acc[4] = {};
    f32x4 acc2[4] = {};

#pragma unroll
    for (int ks = 0; ks < 8; ++ks) {
        int k8 = ks * 32 + lg * 8;
        float4 x0 = *(const float4*)(xrow + k8);
        float4 x1 = *(const float4*)(xrow + k8 + 4);
        bf16x8 a;
        a[0] = (__bf16)x0.x; a[1] = (__bf16)x0.y; a[2] = (__bf16)x0.z; a[3] = (__bf16)x0.w;
        a[4] = (__bf16)x1.x; a[5] = (__bf16)x1.y; a[6] = (__bf16)x1.z; a[7] = (__bf16)x1.w;
#pragma unroll
        for (int nf = 0; nf < 4; ++nf) {
            bf16x8 bf = *(const bf16x8*)(wt_base + ((size_t)(nf * 16 + l15)) * CIN_ + k8);
            acc[nf] = __builtin_amdgcn_mfma_f32_16x16x32_bf16(a, bf, acc[nf], 0, 0, 0);
        }
        if (do_xo) {
#pragma unroll
            for (int nf = 0; nf < 4; ++nf) {
                bf16x8 bf = *(const bf16x8*)(WoT + ((size_t)(nf * 16 + l15)) * CIN_ + k8);
                acc2[nf] = __builtin_amdgcn_mfma_f32_16x16x32_bf16(a, bf, acc2[nf], 0, 0, 0);
            }
        }
    }

    // --- logit epilogue: factored exp2 forms ---
    float alv[4], arv[4];
#pragma unroll
    for (int nf = 0; nf < 4; ++nf) {
        alv[nf] = al[r * D_ + nf * 16 + l15];
        arv[nf] = ar[r * D_ + nf * 16 + l15];
    }
#pragma unroll
    for (int reg = 0; reg < 4; ++reg) {
        float pi = 0.f, pj = 0.f;
#pragma unroll
        for (int nf = 0; nf < 4; ++nf) {
            float v = acc[nf][reg];
            pi += v * alv[nf];
            pj += v * arv[nf];
        }
#pragma unroll
        for (int m = 1; m < 16; m <<= 1) {
            pi += __shfl_xor(pi, m, 64);
            pj += __shfl_xor(pj, m, 64);
        }
        if (l15 == 0) {
            int i = n0 + w * 16 + lg * 4 + reg;
            size_t eoff = ((size_t)((r * B_ + b) * NH_ + ct)) * N_ + i;
            float si = pi * LOG2E, sj = pj * LOG2E;
            eip[eoff] = __builtin_amdgcn_exp2f(si);
            ein[eoff] = __builtin_amdgcn_exp2f(LEAKY * si);
            unsigned lo = f2bf_bits(__builtin_amdgcn_exp2f(sj));
            unsigned hi = f2bf_bits(__builtin_amdgcn_exp2f(LEAKY * sj));
            ej2[eoff] = lo | (hi << 16);
        }
    }

    // --- xo store (r==0, head==0 blocks) ---
    if (do_xo) {
#pragma unroll
        for (int nf = 0; nf < 4; ++nf)
#pragma unroll
            for (int reg = 0; reg < 4; ++reg) {
                int row = n0 + w * 16 + lg * 4 + reg;
                xo[((size_t)(b * N_ + row)) * D_ + nf * 16 + l15] = acc2[nf][reg];
            }
    }

    // --- V store in MFMA-B-fragment tile order via LDS transpose ---
#pragma unroll
    for (int nf = 0; nf < 4; ++nf)
#pragma unroll
        for (int reg = 0; reg < 4; ++reg)
            lds2[w * 16 + lg * 4 + reg][nf * 16 + l15] = f2bf_bits(acc[nf][reg]);
    __syncthreads();

    size_t hb = ((size_t)((r * B_ + b) * NH_ + ct)) * (size_t)(D_ * N_) + (size_t)itile * 4096;
#pragma unroll
    for (int it = 0; it < 4; ++it) {
        int f4 = it * 256 + tid;               // 0..1023 (ushort4 index)
        int e4  = f4 & 1;
        int ll  = (f4 >> 1) & 63;
        int nf  = (f4 >> 7) & 3;
        int jtl = f4 >> 9;
        int col = nf * 16 + (ll & 15);
        int rowb = jtl * 32 + ((ll >> 4) * 8) + e4 * 4;
        ushort4 v;
        v.x = lds2[rowb + 0][col];
        v.y = lds2[rowb + 1][col];
        v.z = lds2[rowb + 2][col];
        v.w = lds2[rowb + 3][col];
        *(ushort4*)(Vt + hb + (size_t)f4 * 4) = v;
    }
}

// ---------------- K2: bitmask attention, barrier-free j-loop ----------------
// grid: R*B*(N/16) = 768 blocks of 512 threads (8 waves: h = w&3, qh = w>>2)
__global__ __launch_bounds__(512, 6) void k2_attn(const float* __restrict__ adjs,
                                                  const unsigned short* __restrict__ vt2,
                                                  const float* __restrict__ eip,
                                                  const float* __restrict__ ein,
                                                  const unsigned int* __restrict__ ej2,
                                                  float* __restrict__ num) {
    __shared__ unsigned int bits_lds[IT2_ * BROW_];     // [row][65] u32 (64 data + pad)
    __shared__ float accsh[NH_ * IT2_ * 64];            // 16 KB cross-q merge
    __shared__ float den_sh[2][NH_][IT2_];

    int x = blockIdx.x;
    x = (x & 7) * 96 + (x >> 3);           // XCD-chunked swizzle (768 = 8*96, bijective)
    int itile = x & 127;
    int b = (x >> 7) & 1;
    int r = x >> 8;
    int tid = threadIdx.x;
    int l = tid & 63;
    int w = tid >> 6;
    int h = w & 3;                         // head
    int qh = w >> 2;                       // j-half
    int l15 = l & 15;
    int lg = l >> 4;
    int i0 = itile * IT2_;

    // ---------- prologue: ballot-pack 16 adj rows into LDS bits ----------
    // wave w packs rows 2w and 2w+1: lane l reads col jc*64+l (coalesced 256B)
    {
        const float* arow = adjs + ((size_t)(r * B_ + b)) * N_ * N_
                          + (size_t)(i0 + 2 * w) * N_;
        unsigned int lo0 = 0, hi0 = 0, lo1 = 0, hi1 = 0;
#pragma unroll 4
        for (int jc = 0; jc < 32; ++jc) {
            float v0 = arow[jc * 64 + l];
            float v1 = arow[N_ + jc * 64 + l];
            unsigned long long m0 = __ballot(v0 != 0.f);
            unsigned long long m1 = __ballot(v1 != 0.f);
            if (l == jc) {
                lo0 = (unsigned int)m0; hi0 = (unsigned int)(m0 >> 32);
                lo1 = (unsigned int)m1; hi1 = (unsigned int)(m1 >> 32);
            }
        }
        if (l < 32) {
            // u32 word k covers cols k*32..k*32+31; lane l holds words 2l, 2l+1
            bits_lds[(2 * w) * BROW_ + 2 * l]         = lo0;
            bits_lds[(2 * w) * BROW_ + 2 * l + 1]     = hi0;
            bits_lds[(2 * w + 1) * BROW_ + 2 * l]     = lo1;
            bits_lds[(2 * w + 1) * BROW_ + 2 * l + 1] = hi1;
        }
    }
    __syncthreads();                       // the ONLY pre-epilogue barrier

    size_t rowoff = ((size_t)((r * B_ + b) * NH_ + h)) * N_;
    const unsigned int* ej2b = ej2 + rowoff + qh * 1024;
    float eipv = eip[rowoff + i0 + l15];
    float einv = ein[rowoff + i0 + l15];
    const unsigned short* vtb = vt2 + ((size_t)((r * B_ + b) * NH_ + h)) * (size_t)(D_ * N_);
    const unsigned int* bitrow = &bits_lds[l15 * BROW_ + qh * 32];  // 32 u32 for this half

    // ones B-frag (col 0) for den-via-MFMA
    bf16x8 onesb;
    {
        __bf16 o1 = (l15 == 0) ? (__bf16)1.0f : (__bf16)0.0f;
#pragma unroll
        for (int e = 0; e < 8; ++e) onesb[e] = o1;
    }

    f32x4 acc[4] = {};
    f32x4 accD = {};

    // ---------- barrier-free j-loop: 32 subs of 32 j ----------
#pragma unroll 4
    for (int s = 0; s < 32; ++s) {
        unsigned int wbits = bitrow[s];                 // LDS b32
        unsigned int b8 = (wbits >> (lg * 8)) & 0xffu;  // this lane's 8 edges
        int jl = s * 32 + lg * 8;
        uint4 u0 = *(const uint4*)(ej2b + jl);
        uint4 u1 = *(const uint4*)(ej2b + jl + 4);
        int jt = qh * 32 + s;
        bf16x8 vf0 = *(const bf16x8*)(vtb + ((size_t)(jt * 4 + 0) * 64 + l) * 8);
        bf16x8 vf1 = *(const bf16x8*)(vtb + ((size_t)(jt * 4 + 1) * 64 + l) * 8);
        bf16x8 vf2 = *(const bf16x8*)(vtb + ((size_t)(jt * 4 + 2) * 64 + l) * 8);
        bf16x8 vf3 = *(const bf16x8*)(vtb + ((size_t)(jt * 4 + 3) * 64 + l) * 8);

        unsigned uv[8] = {u0.x, u0.y, u0.z, u0.w, u1.x, u1.y, u1.z, u1.w};
        bf16x8 af;
#pragma unroll
        for (int e = 0; e < 8; ++e) {
            // adj * exp2(lrelu(ei+ej)) == bit ? max(eip*ejp, ein*ejn) : 0
            float pj = __builtin_bit_cast(float, uv[e] << 16);
            float nj = __builtin_bit_cast(float, uv[e] & 0xffff0000u);
            float val = fmaxf(eipv * pj, einv * nj);
            af[e] = (b8 & (1u << e)) ? (__bf16)val : (__bf16)0.0f;
        }
        accD = __builtin_amdgcn_mfma_f32_16x16x32_bf16(af, onesb, accD, 0, 0, 0);
        acc[0] = __builtin_amdgcn_mfma_f32_16x16x32_bf16(af, vf0, acc[0], 0, 0, 0);
        acc[1] = __builtin_amdgcn_mfma_f32_16x16x32_bf16(af, vf1, acc[1], 0, 0, 0);
        acc[2] = __builtin_amdgcn_mfma_f32_16x16x32_bf16(af, vf2, acc[2], 0, 0, 0);
        acc[3] = __builtin_amdgcn_mfma_f32_16x16x32_bf16(af, vf3, acc[3], 0, 0, 0);
    }

    // --- block-level denominator: accD col 0 lives in lanes l15==0 ---
    if (l15 == 0) {
#pragma unroll
        for (int reg = 0; reg < 4; ++reg)
            den_sh[qh][h][lg * 4 + reg] = accD[reg];
    }
    __syncthreads();
    float inv[4];
#pragma unroll
    for (int reg = 0; reg < 4; ++reg) {
        float dd = den_sh[0][h][lg * 4 + reg] + den_sh[1][h][lg * 4 + reg];
        inv[reg] = dd > 0.f ? 1.0f / dd : 0.f;
    }

    // --- cross-q merge in LDS, then disjoint store to num[r] ---
    if (qh == 1) {
#pragma unroll
        for (int nf = 0; nf < 4; ++nf)
#pragma unroll
            for (int reg = 0; reg < 4; ++reg)
                accsh[(h * 16 + lg * 4 + reg) * 64 + nf * 16 + l15] = acc[nf][reg] * inv[reg];
    }
    __syncthreads();
    if (qh == 0) {
        float* nb = num + ((size_t)((r * B_ + b) * N_ + i0)) * NHD_ + h * 64;
#pragma unroll
        for (int nf = 0; nf < 4; ++nf)
#pragma unroll
            for (int reg = 0; reg < 4; ++reg) {
                float v = acc[nf][reg] * inv[reg]
                        + accsh[(h * 16 + lg * 4 + reg) * 64 + nf * 16 + l15];
                nb[(size_t)(lg * 4 + reg) * NHD_ + nf * 16 + l15] = v;
            }
    }
}

// ---------------- K3: out = xo_broadcast + sum_r num[r] ----------------
__global__ void k3_out(const float* __restrict__ num,
                       const float* __restrict__ xo,
                       float* __restrict__ out) {
    size_t o = (size_t)blockIdx.x * 256 + threadIdx.x;   // < 1048576
    int b = (int)(o >> 19);
    int n = (int)(o >> 8) & 2047;
    int c = (int)(o & 255);
    constexpr size_t RS = (size_t)B_ * N_ * NHD_;
    float v = xo[((size_t)(b * N_ + n)) * D_ + (c & 63)];
    out[o] = v + num[o] + num[o + RS] + num[o + 2 * RS];
}

extern "C" void kernel_launch(void* const* d_in, const int* in_sizes, int n_in,
                              void* d_out, int out_size, void* d_ws, size_t ws_size,
                              hipStream_t stream) {
    const float* xs   = (const float*)d_in[0];
    const float* adjs = (const float*)d_in[1];
    const float* W    = (const float*)d_in[2];
    const float* al   = (const float*)d_in[3];
    const float* ar   = (const float*)d_in[4];
    const float* Wout = (const float*)d_in[5];
    float* out = (float*)d_out;

    char* ws = (char*)d_ws;
    unsigned short* Wt  = (unsigned short*)(ws + OFF_WT);
    unsigned short* WoT = (unsigned short*)(ws + OFF_WOT);
    unsigned short* Vt  = (unsigned short*)(ws + OFF_VT);
    float* eip = (float*)(ws + OFF_EIP);
    float* ein = (float*)(ws + OFF_EIN);
    unsigned int* ej2 = (unsigned int*)(ws + OFF_EJ2);
    float* xo  = (float*)(ws + OFF_XO);
    float* num = (float*)(ws + OFF_NUM);

    k0_wt<<<dim3(832), dim3(256), 0, stream>>>(W, Wout, Wt, WoT);
    k1_hs<<<dim3(R_ * B_ * 32 * 4), dim3(256), 0, stream>>>(xs, Wt, WoT, al, ar, Vt, eip, ein, ej2, xo);
    k2_attn<<<dim3(R_ * B_ * (N_ / IT2_)), dim3(512), 0, stream>>>(adjs, Vt, eip, ein, ej2, num);
    k3_out<<<dim3((B_ * N_ * NHD_) / 256), dim3(256), 0, stream>>>(num, xo, out);
}

// Round 10
// 82.685 us; speedup vs baseline: 1.4279x; 1.4279x over previous
//
#include <hip/hip_runtime.h>

// Relation Graph Attention (RGAT), MI355X. v10 (= v9 + ej2-in-LDS + manual
// 2-deep vt2 register prefetch; barrier-free j-loop).
// R=3, B=2, N=2048, CIN=256, NH=4, D=64.

constexpr int R_ = 3, B_ = 2, N_ = 2048, CIN_ = 256, NH_ = 4, D_ = 64, NHD_ = 256;
constexpr int IT2_ = 16;               // i rows per K2 block
constexpr int BROW_ = 65;              // u32 per bitmask row (64 data + 1 pad)
constexpr float LEAKY = 0.1f;
constexpr float LOG2E = 1.4426950408889634f;

typedef float f32x4 __attribute__((ext_vector_type(4)));
typedef __bf16 bf16x8 __attribute__((ext_vector_type(8)));

// workspace layout (bytes)
constexpr size_t OFF_WT  = 0;                                      // ushort [R][NHD][CIN]
constexpr size_t SZ_WT   = (size_t)R_ * NHD_ * CIN_ * 2;           // 393216
constexpr size_t OFF_WOT = OFF_WT + SZ_WT;                         // ushort [D][CIN]
constexpr size_t SZ_WOT  = (size_t)D_ * CIN_ * 2;                  // 32768
constexpr size_t OFF_VT  = OFF_WOT + SZ_WOT;                       // ushort, frag-tiled
constexpr size_t SZ_VT   = (size_t)R_ * B_ * NH_ * D_ * N_ * 2;
constexpr size_t SZ_E    = (size_t)R_ * B_ * NH_ * N_ * 4;         // [R][B][NH][N]
constexpr size_t OFF_EIP = OFF_VT + SZ_VT;
constexpr size_t OFF_EIN = OFF_EIP + SZ_E;
constexpr size_t OFF_EJ2 = OFF_EIN + SZ_E;                         // u32 packed bf16 pair
constexpr size_t OFF_XO  = OFF_EJ2 + SZ_E;                         // float [B][N][D]
constexpr size_t SZ_XO   = (size_t)B_ * N_ * D_ * 4;
constexpr size_t OFF_NUM = OFF_XO + SZ_XO;                         // float [R][B][N][NHD]

__device__ __forceinline__ unsigned short f2bf_bits(float f) {
    __bf16 b = (__bf16)f;
    return __builtin_bit_cast(unsigned short, b);
}

// ---------------- K0: transpose+cast W and Wout ----------------
__global__ void k0_wt(const float* __restrict__ W, const float* __restrict__ Wout,
                      unsigned short* __restrict__ Wt, unsigned short* __restrict__ WoT) {
    int of = blockIdx.x * 256 + threadIdx.x;       // 0..212991
    if (of < 196608) {
        int r = of >> 16;
        int rem = of & 65535;
        int o = rem >> 8;
        int k = rem & 255;
        Wt[of] = f2bf_bits(W[((size_t)(r * CIN_ + k)) * NHD_ + o]);
    } else {
        int idx = of - 196608;                     // 0..16383
        int o = idx >> 8, k = idx & 255;
        WoT[idx] = f2bf_bits(Wout[k * D_ + o]);
    }
}

// ---------------- K1: per-head hs GEMM + factored-exp epilogue + frag-tiled V ----------------
// grid: R*B*32*4 = 768 blocks, 256 threads (4 waves x 16 rows); head = blockIdx&3
__global__ __launch_bounds__(256) void k1_hs(const float* __restrict__ xs,
                                             const unsigned short* __restrict__ Wt,
                                             const unsigned short* __restrict__ WoT,
                                             const float* __restrict__ al,
                                             const float* __restrict__ ar,
                                             unsigned short* __restrict__ Vt,
                                             float* __restrict__ eip,
                                             float* __restrict__ ein,
                                             unsigned int* __restrict__ ej2,
                                             float* __restrict__ xo) {
    __shared__ unsigned short lds2[64][72];

    int x = blockIdx.x;
    int ct = x & 3;                        // head
    int itile = (x >> 2) & 31;
    int b = (x >> 7) & 1;
    int r = x >> 8;
    int tid = threadIdx.x;
    int l = tid & 63;
    int w = tid >> 6;
    int l15 = l & 15;
    int lg = l >> 4;
    int n0 = itile * 64;
    bool do_xo = (r == 0) && (ct == 0);

    const float* xrow = xs + ((size_t)(b * N_ + n0 + w * 16 + l15)) * CIN_;
    const unsigned short* wt_base = Wt + ((size_t)r * NHD_ + ct * 64) * CIN_;

    f32x4 acc[4] = {};
    f32x4 acc2[4] = {};

#pragma unroll
    for (int ks = 0; ks < 8; ++ks) {
        int k8 = ks * 32 + lg * 8;
        float4 x0 = *(const float4*)(xrow + k8);
        float4 x1 = *(const float4*)(xrow + k8 + 4);
        bf16x8 a;
        a[0] = (__bf16)x0.x; a[1] = (__bf16)x0.y; a[2] = (__bf16)x0.z; a[3] = (__bf16)x0.w;
        a[4] = (__bf16)x1.x; a[5] = (__bf16)x1.y; a[6] = (__bf16)x1.z; a[7] = (__bf16)x1.w;
#pragma unroll
        for (int nf = 0; nf < 4; ++nf) {
            bf16x8 bf = *(const bf16x8*)(wt_base + ((size_t)(nf * 16 + l15)) * CIN_ + k8);
            acc[nf] = __builtin_amdgcn_mfma_f32_16x16x32_bf16(a, bf, acc[nf], 0, 0, 0);
        }
        if (do_xo) {
#pragma unroll
            for (int nf = 0; nf < 4; ++nf) {
                bf16x8 bf = *(const bf16x8*)(WoT + ((size_t)(nf * 16 + l15)) * CIN_ + k8);
                acc2[nf] = __builtin_amdgcn_mfma_f32_16x16x32_bf16(a, bf, acc2[nf], 0, 0, 0);
            }
        }
    }

    // --- logit epilogue: factored exp2 forms ---
    float alv[4], arv[4];
#pragma unroll
    for (int nf = 0; nf < 4; ++nf) {
        alv[nf] = al[r * D_ + nf * 16 + l15];
        arv[nf] = ar[r * D_ + nf * 16 + l15];
    }
#pragma unroll
    for (int reg = 0; reg < 4; ++reg) {
        float pi = 0.f, pj = 0.f;
#pragma unroll
        for (int nf = 0; nf < 4; ++nf) {
            float v = acc[nf][reg];
            pi += v * alv[nf];
            pj += v * arv[nf];
        }
#pragma unroll
        for (int m = 1; m < 16; m <<= 1) {
            pi += __shfl_xor(pi, m, 64);
            pj += __shfl_xor(pj, m, 64);
        }
        if (l15 == 0) {
            int i = n0 + w * 16 + lg * 4 + reg;
            size_t eoff = ((size_t)((r * B_ + b) * NH_ + ct)) * N_ + i;
            float si = pi * LOG2E, sj = pj * LOG2E;
            eip[eoff] = __builtin_amdgcn_exp2f(si);
            ein[eoff] = __builtin_amdgcn_exp2f(LEAKY * si);
            unsigned lo = f2bf_bits(__builtin_amdgcn_exp2f(sj));
            unsigned hi = f2bf_bits(__builtin_amdgcn_exp2f(LEAKY * sj));
            ej2[eoff] = lo | (hi << 16);
        }
    }

    // --- xo store (r==0, head==0 blocks) ---
    if (do_xo) {
#pragma unroll
        for (int nf = 0; nf < 4; ++nf)
#pragma unroll
            for (int reg = 0; reg < 4; ++reg) {
                int row = n0 + w * 16 + lg * 4 + reg;
                xo[((size_t)(b * N_ + row)) * D_ + nf * 16 + l15] = acc2[nf][reg];
            }
    }

    // --- V store in MFMA-B-fragment tile order via LDS transpose ---
#pragma unroll
    for (int nf = 0; nf < 4; ++nf)
#pragma unroll
        for (int reg = 0; reg < 4; ++reg)
            lds2[w * 16 + lg * 4 + reg][nf * 16 + l15] = f2bf_bits(acc[nf][reg]);
    __syncthreads();

    size_t hb = ((size_t)((r * B_ + b) * NH_ + ct)) * (size_t)(D_ * N_) + (size_t)itile * 4096;
#pragma unroll
    for (int it = 0; it < 4; ++it) {
        int f4 = it * 256 + tid;               // 0..1023 (ushort4 index)
        int e4  = f4 & 1;
        int ll  = (f4 >> 1) & 63;
        int nf  = (f4 >> 7) & 3;
        int jtl = f4 >> 9;
        int col = nf * 16 + (ll & 15);
        int rowb = jtl * 32 + ((ll >> 4) * 8) + e4 * 4;
        ushort4 v;
        v.x = lds2[rowb + 0][col];
        v.y = lds2[rowb + 1][col];
        v.z = lds2[rowb + 2][col];
        v.w = lds2[rowb + 3][col];
        *(ushort4*)(Vt + hb + (size_t)f4 * 4) = v;
    }
}

// ---------------- K2: bitmask attention, barrier-free pipelined j-loop ----------------
// grid: R*B*(N/16) = 768 blocks of 512 threads (8 waves: h = w&3, qh = w>>2)
__global__ __launch_bounds__(512, 4) void k2_attn(const float* __restrict__ adjs,
                                                  const unsigned short* __restrict__ vt2,
                                                  const float* __restrict__ eip,
                                                  const float* __restrict__ ein,
                                                  const unsigned int* __restrict__ ej2,
                                                  float* __restrict__ num) {
    __shared__ unsigned int bits_lds[IT2_ * BROW_];     // [row][65] u32
    __shared__ unsigned int ej_lds[NH_][N_];            // 32 KB packed ej factors
    __shared__ float accsh[NH_ * IT2_ * 64];            // 16 KB cross-q merge
    __shared__ float den_sh[2][NH_][IT2_];

    int x = blockIdx.x;
    x = (x & 7) * 96 + (x >> 3);           // XCD-chunked swizzle (768 = 8*96, bijective)
    int itile = x & 127;
    int b = (x >> 7) & 1;
    int r = x >> 8;
    int tid = threadIdx.x;
    int l = tid & 63;
    int w = tid >> 6;
    int h = w & 3;                         // head
    int qh = w >> 2;                       // j-half
    int l15 = l & 15;
    int lg = l >> 4;
    int i0 = itile * IT2_;

    // ---------- prologue A: ballot-pack 16 adj rows into LDS bits ----------
    {
        const float* arow = adjs + ((size_t)(r * B_ + b)) * N_ * N_
                          + (size_t)(i0 + 2 * w) * N_;
        unsigned int lo0 = 0, hi0 = 0, lo1 = 0, hi1 = 0;
#pragma unroll 4
        for (int jc = 0; jc < 32; ++jc) {
            float v0 = arow[jc * 64 + l];
            float v1 = arow[N_ + jc * 64 + l];
            unsigned long long m0 = __ballot(v0 != 0.f);
            unsigned long long m1 = __ballot(v1 != 0.f);
            if (l == jc) {
                lo0 = (unsigned int)m0; hi0 = (unsigned int)(m0 >> 32);
                lo1 = (unsigned int)m1; hi1 = (unsigned int)(m1 >> 32);
            }
        }
        if (l < 32) {
            bits_lds[(2 * w) * BROW_ + 2 * l]         = lo0;
            bits_lds[(2 * w) * BROW_ + 2 * l + 1]     = hi0;
            bits_lds[(2 * w + 1) * BROW_ + 2 * l]     = lo1;
            bits_lds[(2 * w + 1) * BROW_ + 2 * l + 1] = hi1;
        }
    }
    // ---------- prologue B: ej2 -> LDS (coalesced, 16 u32/thread) ----------
    {
        int hh = tid >> 7;                 // 0..3
        int t128 = tid & 127;
        const uint4* src = (const uint4*)(ej2 + ((size_t)((r * B_ + b) * NH_ + hh)) * N_) + t128 * 4;
        uint4* dst = (uint4*)&ej_lds[hh][t128 * 16];
        uint4 a0 = src[0], a1 = src[1], a2 = src[2], a3 = src[3];
        dst[0] = a0; dst[1] = a1; dst[2] = a2; dst[3] = a3;
    }
    __syncthreads();                       // the ONLY pre-epilogue barrier

    size_t rowoff = ((size_t)((r * B_ + b) * NH_ + h)) * N_;
    float eipv = eip[rowoff + i0 + l15];
    float einv = ein[rowoff + i0 + l15];
    const unsigned short* vtb = vt2 + ((size_t)((r * B_ + b) * NH_ + h)) * (size_t)(D_ * N_);
    const unsigned int* bitrow = &bits_lds[l15 * BROW_ + qh * 32];
    const unsigned int* ejl = &ej_lds[h][qh * 1024];

    // ones B-frag (col 0) for den-via-MFMA
    bf16x8 onesb;
    {
        __bf16 o1 = (l15 == 0) ? (__bf16)1.0f : (__bf16)0.0f;
#pragma unroll
        for (int e = 0; e < 8; ++e) onesb[e] = o1;
    }

    f32x4 acc[4] = {};
    f32x4 accD = {};

    // 4 nf-frags per sub: one base address + 1KB immediate offsets
    auto LOADV = [&](bf16x8 (&vf)[4], int s) {
        const bf16x8* p = (const bf16x8*)(vtb + (((size_t)(qh * 32 + s) * 4) * 64 + l) * 8);
        vf[0] = p[0];
        vf[1] = p[64];
        vf[2] = p[128];
        vf[3] = p[192];
    };

    auto COMPUTE = [&](bf16x8 (&vf)[4], int s) {
        unsigned int wbits = bitrow[s];
        unsigned int b8 = (wbits >> (lg * 8)) & 0xffu;
        const uint4* ep = (const uint4*)(ejl + s * 32 + lg * 8);
        uint4 u0 = ep[0];
        uint4 u1 = ep[1];
        unsigned uv[8] = {u0.x, u0.y, u0.z, u0.w, u1.x, u1.y, u1.z, u1.w};
        bf16x8 af;
#pragma unroll
        for (int e = 0; e < 8; ++e) {
            // adj * exp2(lrelu(ei+ej)) == bit ? max(eip*ejp, ein*ejn) : 0
            float pj = __builtin_bit_cast(float, uv[e] << 16);
            float nj = __builtin_bit_cast(float, uv[e] & 0xffff0000u);
            float val = fmaxf(eipv * pj, einv * nj);
            af[e] = (b8 & (1u << e)) ? (__bf16)val : (__bf16)0.0f;
        }
        accD = __builtin_amdgcn_mfma_f32_16x16x32_bf16(af, onesb, accD, 0, 0, 0);
        acc[0] = __builtin_amdgcn_mfma_f32_16x16x32_bf16(af, vf[0], acc[0], 0, 0, 0);
        acc[1] = __builtin_amdgcn_mfma_f32_16x16x32_bf16(af, vf[1], acc[1], 0, 0, 0);
        acc[2] = __builtin_amdgcn_mfma_f32_16x16x32_bf16(af, vf[2], acc[2], 0, 0, 0);
        acc[3] = __builtin_amdgcn_mfma_f32_16x16x32_bf16(af, vf[3], acc[3], 0, 0, 0);
    };

    // ---------- barrier-free j-loop, 2-deep register pipeline ----------
    bf16x8 vfA[4], vfB[4];
    LOADV(vfA, 0);
    for (int s = 0; s < 32; s += 2) {
        LOADV(vfB, s + 1);                 // in flight across COMPUTE A
        COMPUTE(vfA, s);
        if (s + 2 < 32) LOADV(vfA, s + 2); // in flight across COMPUTE B
        COMPUTE(vfB, s + 1);
    }

    // --- block-level denominator: accD col 0 lives in lanes l15==0 ---
    if (l15 == 0) {
#pragma unroll
        for (int reg = 0; reg < 4; ++reg)
            den_sh[qh][h][lg * 4 + reg] = accD[reg];
    }
    __syncthreads();
    float inv[4];
#pragma unroll
    for (int reg = 0; reg < 4; ++reg) {
        float dd = den_sh[0][h][lg * 4 + reg] + den_sh[1][h][lg * 4 + reg];
        inv[reg] = dd > 0.f ? 1.0f / dd : 0.f;
    }

    // --- cross-q merge in LDS, then disjoint store to num[r] ---
    if (qh == 1) {
#pragma unroll
        for (int nf = 0; nf < 4; ++nf)
#pragma unroll
            for (int reg = 0; reg < 4; ++reg)
                accsh[(h * 16 + lg * 4 + reg) * 64 + nf * 16 + l15] = acc[nf][reg] * inv[reg];
    }
    __syncthreads();
    if (qh == 0) {
        float* nb = num + ((size_t)((r * B_ + b) * N_ + i0)) * NHD_ + h * 64;
#pragma unroll
        for (int nf = 0; nf < 4; ++nf)
#pragma unroll
            for (int reg = 0; reg < 4; ++reg) {
                float v = acc[nf][reg] * inv[reg]
                        + accsh[(h * 16 + lg * 4 + reg) * 64 + nf * 16 + l15];
                nb[(size_t)(lg * 4 + reg) * NHD_ + nf * 16 + l15] = v;
            }
    }
}

// ---------------- K3: out = xo_broadcast + sum_r num[r] ----------------
__global__ void k3_out(const float* __restrict__ num,
                       const float* __restrict__ xo,
                       float* __restrict__ out) {
    size_t o = (size_t)blockIdx.x * 256 + threadIdx.x;   // < 1048576
    int b = (int)(o >> 19);
    int n = (int)(o >> 8) & 2047;
    int c = (int)(o & 255);
    constexpr size_t RS = (size_t)B_ * N_ * NHD_;
    float v = xo[((size_t)(b * N_ + n)) * D_ + (c & 63)];
    out[o] = v + num[o] + num[o + RS] + num[o + 2 * RS];
}

extern "C" void kernel_launch(void* const* d_in, const int* in_sizes, int n_in,
                              void* d_out, int out_size, void* d_ws, size_t ws_size,
                              hipStream_t stream) {
    const float* xs   = (const float*)d_in[0];
    const float* adjs = (const float*)d_in[1];
    const float* W    = (const float*)d_in[2];
    const float* al   = (const float*)d_in[3];
    const float* ar   = (const float*)d_in[4];
    const float* Wout = (const float*)d_in[5];
    float* out = (float*)d_out;

    char* ws = (char*)d_ws;
    unsigned short* Wt  = (unsigned short*)(ws + OFF_WT);
    unsigned short* WoT = (unsigned short*)(ws + OFF_WOT);
    unsigned short* Vt  = (unsigned short*)(ws + OFF_VT);
    float* eip = (float*)(ws + OFF_EIP);
    float* ein = (float*)(ws + OFF_EIN);
    unsigned int* ej2 = (unsigned int*)(ws + OFF_EJ2);
    float* xo  = (float*)(ws + OFF_XO);
    float* num = (float*)(ws + OFF_NUM);

    k0_wt<<<dim3(832), dim3(256), 0, stream>>>(W, Wout, Wt, WoT);
    k1_hs<<<dim3(R_ * B_ * 32 * 4), dim3(256), 0, stream>>>(xs, Wt, WoT, al, ar, Vt, eip, ein, ej2, xo);
    k2_attn<<<dim3(R_ * B_ * (N_ / IT2_)), dim3(512), 0, stream>>>(adjs, Vt, eip, ein, ej2, num);
    k3_out<<<dim3((B_ * N_ * NHD_) / 256), dim3(256), 0, stream>>>(num, xo, out);
}